// Round 9
// baseline (1717.348 us; speedup 1.0000x reference)
//
#include <hip/hip_runtime.h>
#include <hip/hip_bf16.h>

#define N_NODES   100000
#define N_EDGES   1600000
#define FDIM      128
#define N_GRAPHS  1024
#define N_CLASSES 32
#define SCAN_BLK  1024
#define M_PAD     100032            // padded rows for 64-row GEMM tiles
#define SLICE_U   (M_PAD * 8)       // uints per 16-feature slice (32B rows)
#define NS        16                // record slots per node (4 lanes each)

typedef __attribute__((ext_vector_type(8))) short short8v;
typedef __attribute__((ext_vector_type(4))) float f32x4;
typedef __attribute__((ext_vector_type(2))) unsigned uint2v;

__device__ __forceinline__ float bflo(unsigned u){ union{unsigned i; float f;} c; c.i = u << 16; return c.f; }
__device__ __forceinline__ float bfhi(unsigned u){ union{unsigned i; float f;} c; c.i = u & 0xffff0000u; return c.f; }
__device__ __forceinline__ unsigned short f2bf(float f){
    union{float f; unsigned u;} c{f};
    return (unsigned short)((c.u + 0x7fffu + ((c.u >> 16) & 1u)) >> 16);
}
__device__ __forceinline__ unsigned packbf2(float a, float b){
    return (unsigned)f2bf(a) | ((unsigned)f2bf(b) << 16);
}

// ---------------------------------------------------------------------------
// fp32 x[v][128] * dinv[v] -> bf16x2 XCD-sliced X' table
__global__ void k_f2bf(const float* __restrict__ in, const float* __restrict__ dinv,
                       unsigned* __restrict__ out, int n2) {
    int i = blockIdx.x * blockDim.x + threadIdx.x;
    if (i < n2) {
        float2 v2 = ((const float2*)in)[i];
        int v = i >> 6, jp = i & 63;
        int f = jp >> 3, off = jp & 7;
        float dv = dinv[v];
        __builtin_nontemporal_store(packbf2(v2.x * dv, v2.y * dv),
                                    out + (size_t)f * SLICE_U + (size_t)v * 8 + off);
    }
}

__global__ void k_wt(const float* __restrict__ W, unsigned short* __restrict__ Wt) {
    int i = blockIdx.x * blockDim.x + threadIdx.x;   // 16384
    int k = i >> 7, n = i & 127;
    Wt[n * 128 + k] = f2bf(W[i]);
}

// ---------------------------------------------------------------------------
__global__ void k_count(const int* __restrict__ dst, int* __restrict__ indeg, int E) {
    int i = blockIdx.x * blockDim.x + threadIdx.x;
    if (i < E) atomicAdd(&indeg[dst[i]], 1);
}

// dinv + per-graph count + contiguous node range [r0,r1) (batch is sorted)
__global__ void k_prep(const int* __restrict__ indeg, float* __restrict__ dinv,
                       const int* __restrict__ batch, int* __restrict__ cnt,
                       int* __restrict__ r0, int* __restrict__ r1, int n) {
    int v = blockIdx.x * blockDim.x + threadIdx.x;
    if (v < n) {
        dinv[v] = rsqrtf((float)(indeg[v] + 1));
        int g = batch[v];
        atomicAdd(&cnt[g], 1);
        atomicMin(&r0[g], v);
        atomicMax(&r1[g], v + 1);
    }
}

__global__ void k_scan1(const int* __restrict__ in, int* __restrict__ out,
                        int* __restrict__ bsums, int n) {
    __shared__ int lds[256];
    int blk = blockIdx.x, t = threadIdx.x;
    int base = blk * SCAN_BLK + t * 4;
    int v[4];
#pragma unroll
    for (int i = 0; i < 4; ++i) v[i] = (base + i < n) ? in[base + i] : 0;
    int local = v[0] + v[1] + v[2] + v[3];
    lds[t] = local;
    __syncthreads();
    for (int off = 1; off < 256; off <<= 1) {
        int x = lds[t];
        int y = (t >= off) ? lds[t - off] : 0;
        __syncthreads();
        lds[t] = x + y;
        __syncthreads();
    }
    int excl = lds[t] - local;
    if (t == 255) bsums[blk] = lds[255];
    int run = excl;
#pragma unroll
    for (int i = 0; i < 4; ++i) {
        if (base + i < n) { out[base + i] = run; run += v[i]; }
    }
}

__global__ void k_scan2(int* __restrict__ bsums, int nb) {
    __shared__ int lds[256];
    int t = threadIdx.x;
    int orig = (t < nb) ? bsums[t] : 0;
    lds[t] = orig;
    __syncthreads();
    for (int off = 1; off < 256; off <<= 1) {
        int x = lds[t];
        int y = (t >= off) ? lds[t - off] : 0;
        __syncthreads();
        lds[t] = x + y;
        __syncthreads();
    }
    if (t < nb) bsums[t] = lds[t] - orig;
}

__global__ void k_scan3(int* __restrict__ rp, const int* __restrict__ boffs, int n, int E) {
    int i = blockIdx.x * blockDim.x + threadIdx.x;
    if (i < n) rp[i] += boffs[i / SCAN_BLK];
    if (i == n) rp[n] = E;
}

// CSR fill: col only (weights folded into the pre-scaled tables)
__global__ void k_fill(const int* __restrict__ src, const int* __restrict__ dst,
                       const int* __restrict__ rp, int* __restrict__ cursor,
                       int* __restrict__ col, int E) {
    int i = blockIdx.x * blockDim.x + threadIdx.x;
    if (i < E) {
        int d = dst[i];
        int p = atomicAdd(&cursor[d], 1);
        col[rp[d] + p] = src[i];
    }
}

// ---------------------------------------------------------------------------
// XCD-sliced gather: slice f = blockIdx&7 (3.2MB slice L2-resident on XCD f).
// Wave = 16 slots x 4 lanes (uint2 = 8B each -> 32B row per slot). Per 8-node
// batch: all 16+16 col loads and 16+16 gathers issued upfront (deep MLP);
// slot 0 = self record. 4-round butterfly over slots. out = dv * (sum X'[s]).
#define AGG2_CORE(XT)                                                            \
    int lane = threadIdx.x & 63;                                                 \
    int wv   = threadIdx.x >> 6;                                                 \
    int f    = blockIdx.x & 7;                                                   \
    int vb   = (blockIdx.x >> 3) * 32 + wv * 8;                                  \
    int ri   = lane >> 2;                                                        \
    int q    = lane & 3;                                                         \
    (void)f;                                                                     \
    int e0[8], Ln[8];                                                            \
    _Pragma("unroll")                                                            \
    for (int n = 0; n < 8; ++n) {                                                \
        e0[n] = rp[vb + n];                                                      \
        Ln[n] = rp[vb + n + 1] - e0[n] + 1;                                      \
    }                                                                            \
    int rec1[8], rec2[8];                                                        \
    _Pragma("unroll")                                                            \
    for (int n = 0; n < 8; ++n) {                                                \
        rec1[n] = -1; rec2[n] = -1;                                              \
        if (ri < Ln[n]) rec1[n] = (ri == 0) ? (vb + n) : col[e0[n] + ri - 1];    \
        if (ri + NS < Ln[n]) rec2[n] = col[e0[n] + ri + NS - 1];                 \
    }                                                                            \
    uint2v u1[8], u2[8];                                                         \
    _Pragma("unroll")                                                            \
    for (int n = 0; n < 8; ++n) {                                                \
        u1[n] = (uint2v){0u, 0u}; u2[n] = (uint2v){0u, 0u};                      \
        if (rec1[n] >= 0) u1[n] = *(const uint2v*)(XT + (size_t)rec1[n] * 8 + q * 2); \
        if (rec2[n] >= 0) u2[n] = *(const uint2v*)(XT + (size_t)rec2[n] * 8 + q * 2); \
    }                                                                            \
    _Pragma("unroll")                                                            \
    for (int n = 0; n < 8; ++n) {                                                \
        float a0 = bflo(u1[n].x) + bflo(u2[n].x);                                \
        float a1 = bfhi(u1[n].x) + bfhi(u2[n].x);                                \
        float a2 = bflo(u1[n].y) + bflo(u2[n].y);                                \
        float a3 = bfhi(u1[n].y) + bfhi(u2[n].y);                                \
        if (__builtin_expect(Ln[n] > 2 * NS, 0)) {                               \
            for (int b = ri + 2 * NS; b < Ln[n]; b += NS) {                      \
                int s = col[e0[n] + b - 1];                                      \
                uint2v u = *(const uint2v*)(XT + (size_t)s * 8 + q * 2);         \
                a0 += bflo(u.x); a1 += bfhi(u.x);                                \
                a2 += bflo(u.y); a3 += bfhi(u.y);                                \
            }                                                                    \
        }                                                                        \
        _Pragma("unroll")                                                        \
        for (int off = 4; off < 64; off <<= 1) {                                 \
            a0 += __shfl_xor(a0, off, 64);                                       \
            a1 += __shfl_xor(a1, off, 64);                                       \
            a2 += __shfl_xor(a2, off, 64);                                       \
            a3 += __shfl_xor(a3, off, 64);                                       \
        }                                                                        \
        float dvv = dinv[vb + n];                                                \
        a0 *= dvv; a1 *= dvv; a2 *= dvv; a3 *= dvv;

// layer 1: output sliced bf16 A'
__global__ __launch_bounds__(256) void k_aggA(
    const unsigned* __restrict__ Xs, unsigned* __restrict__ Os,
    const int* __restrict__ rp, const int* __restrict__ col,
    const float* __restrict__ dinv)
{
    const unsigned* XT = Xs + (size_t)(blockIdx.x & 7) * SLICE_U;
    unsigned* OT       = Os + (size_t)(blockIdx.x & 7) * SLICE_U;
    AGG2_CORE(XT)
        if (ri == 0) {
            uint2v o;
            o.x = packbf2(a0, a1);
            o.y = packbf2(a2, a3);
            __builtin_nontemporal_store(o, (uint2v*)(OT + (size_t)(vb + n) * 8 + q * 2));
        }
    }
}

// layer 2: output dense f32 Q rows (consumed by fused pool+classifier)
__global__ __launch_bounds__(256) void k_aggQ(
    const unsigned* __restrict__ Xs, float* __restrict__ Q,
    const int* __restrict__ rp, const int* __restrict__ col,
    const float* __restrict__ dinv)
{
    const unsigned* XT = Xs + (size_t)(blockIdx.x & 7) * SLICE_U;
    AGG2_CORE(XT)
        if (ri == 0) {
            f32x4 o = {a0, a1, a2, a3};
            __builtin_nontemporal_store(o,
                (f32x4*)(Q + (size_t)(vb + n) * FDIM + f * 16 + q * 4));
        }
    }
}

// ---------------------------------------------------------------------------
// B = relu(A @ W1 + b1) * dinv[row]  (H' pre-scale folded into epilogue)
__global__ __launch_bounds__(256) void k_gemm_mfma(
    const unsigned short* __restrict__ A, const unsigned short* __restrict__ Wt,
    const float* __restrict__ bias, const float* __restrict__ dinv,
    unsigned short* __restrict__ B)
{
    int lane = threadIdx.x & 63;
    int wv = threadIdx.x >> 6;
    size_t row0 = (size_t)blockIdx.x * 64 + (size_t)wv * 16;
    int r = lane & 15, g = lane >> 4;

    short8v af[4];
#pragma unroll
    for (int ks = 0; ks < 4; ++ks) {
        int fa  = 2 * ks + (g >> 1);          // slice of features ks*32 + g*8
        int off = (g & 1) * 8;
        af[ks] = *(const short8v*)(A + (size_t)fa * SLICE_U * 2 + (row0 + r) * 16 + off);
    }

    f32x4 acc[8];
#pragma unroll
    for (int ct = 0; ct < 8; ++ct) {
        f32x4 a = {0.f, 0.f, 0.f, 0.f};
        const unsigned short* wrow = Wt + (ct * 16 + r) * FDIM + g * 8;
#pragma unroll
        for (int ks = 0; ks < 4; ++ks) {
            short8v bfr = *(const short8v*)(wrow + ks * 32);
            a = __builtin_amdgcn_mfma_f32_16x16x32_bf16(af[ks], bfr, a, 0, 0, 0);
        }
        acc[ct] = a;
    }

#pragma unroll
    for (int ct = 0; ct < 8; ++ct) {
        float bs = bias[ct * 16 + r];
#pragma unroll
        for (int i = 0; i < 4; ++i) {
            size_t row = row0 + g * 4 + i;
            if (row < N_NODES) {
                float vv = fmaxf(acc[ct][i] + bs, 0.f) * dinv[row];
                __builtin_nontemporal_store(f2bf(vv),
                    B + (size_t)ct * SLICE_U * 2 + row * 16 + r);
            }
        }
    }
}

// ---------------------------------------------------------------------------
__global__ void k_wcomb(const float* __restrict__ W2, const float* __restrict__ Wf,
                        const float* __restrict__ b2, const float* __restrict__ bf,
                        float* __restrict__ Wc, float* __restrict__ bc) {
    int idx = blockIdx.x * blockDim.x + threadIdx.x;
    if (idx < 128 * 32) {
        int k = idx >> 5, c = idx & 31;
        float acc = 0.0f;
        for (int m = 0; m < 128; ++m) acc += W2[k * 128 + m] * Wf[m * 32 + c];
        Wc[idx] = acc;
    }
    if (idx < 32) {
        float acc = bf[idx];
        for (int m = 0; m < 128; ++m) acc += b2[m] * Wf[m * 32 + idx];
        bc[idx] = acc;
    }
}

// fused pool + classifier: per graph, stream contiguous Q rows (batch sorted),
// mean, then fold through Wc. Zero atomics.
__global__ __launch_bounds__(128) void k_final(
    const float* __restrict__ Q, const int* __restrict__ cnt,
    const int* __restrict__ r0, const int* __restrict__ r1,
    const float* __restrict__ Wc, const float* __restrict__ bc,
    const float* __restrict__ bf, float* __restrict__ out)
{
    __shared__ float p[128];
    int g = blockIdx.x, t = threadIdx.x;
    int c_ = cnt[g];
    int v0 = r0[g], v1 = r1[g];
    float s0 = 0.f, s1 = 0.f;
    int v = v0;
    for (; v + 1 < v1; v += 2) {
        s0 += Q[(size_t)v * FDIM + t];
        s1 += Q[(size_t)(v + 1) * FDIM + t];
    }
    if (v < v1) s0 += Q[(size_t)v * FDIM + t];
    float inv = (c_ > 0) ? 1.0f / (float)c_ : 0.0f;
    p[t] = (s0 + s1) * inv;
    __syncthreads();
    if (t < N_CLASSES) {
        float acc = (c_ > 0) ? bc[t] : bf[t];
#pragma unroll
        for (int k = 0; k < 128; ++k) acc = fmaf(p[k], Wc[k * 32 + t], acc);
        out[(size_t)g * N_CLASSES + t] = acc;
    }
}

// ---------------------------------------------------------------------------
extern "C" void kernel_launch(void* const* d_in, const int* in_sizes, int n_in,
                              void* d_out, int out_size, void* d_ws, size_t ws_size,
                              hipStream_t stream) {
    const float* x    = (const float*)d_in[0];
    const int*   ei   = (const int*)d_in[1];
    const int*   batch= (const int*)d_in[2];
    const float* W1   = (const float*)d_in[3];
    const float* b1   = (const float*)d_in[4];
    const float* W2   = (const float*)d_in[5];
    const float* b2   = (const float*)d_in[6];
    const float* Wf   = (const float*)d_in[7];
    const float* bf   = (const float*)d_in[8];
    const int* src = ei;
    const int* dst = ei + N_EDGES;

    char* w = (char*)d_ws;
    auto alloc = [&](size_t bytes) { char* p = w; w += (bytes + 255) & ~255ull; return p; };
    int*      indeg  = (int*)     alloc((size_t)N_NODES * 4);
    float*    dinv   = (float*)   alloc((size_t)N_NODES * 4);
    int*      rp     = (int*)     alloc((size_t)(N_NODES + 1) * 4);
    int*      cursor = (int*)     alloc((size_t)N_NODES * 4);
    int*      bsums  = (int*)     alloc(1024 * 4);
    int*      col    = (int*)     alloc((size_t)N_EDGES * 4);
    unsigned* xh     = (unsigned*)alloc((size_t)SLICE_U * 8 * 4);   // sliced bf16x2 X'
    unsigned* Ab     = (unsigned*)alloc((size_t)SLICE_U * 8 * 4);   // sliced bf16x2 A
    unsigned* Bb     = (unsigned*)alloc((size_t)SLICE_U * 8 * 4);   // sliced bf16x2 H'
    unsigned short* Wt = (unsigned short*)alloc(128 * 128 * 2);
    int*      cnt    = (int*)     alloc((size_t)N_GRAPHS * 4);
    int*      r0     = (int*)     alloc((size_t)N_GRAPHS * 4);
    int*      r1     = (int*)     alloc((size_t)N_GRAPHS * 4);
    float*    Wc     = (float*)   alloc(128 * 32 * 4);
    float*    bc     = (float*)   alloc(32 * 4);
    // Q (dense f32 [M_PAD][128], 51.2MB) aliases xh+Ab (dead after GEMM;
    // contiguous and exactly M_PAD*128*4 bytes combined)
    float*    Q      = (float*)xh;

    hipMemsetAsync(indeg,  0,    (size_t)N_NODES * 4, stream);
    hipMemsetAsync(cursor, 0,    (size_t)N_NODES * 4, stream);
    hipMemsetAsync(cnt,    0,    (size_t)N_GRAPHS * 4, stream);
    hipMemsetAsync(r0,     0x7f, (size_t)N_GRAPHS * 4, stream);
    hipMemsetAsync(r1,     0,    (size_t)N_GRAPHS * 4, stream);

    const int nbScan = (N_NODES + SCAN_BLK - 1) / SCAN_BLK;   // 98

    // degrees -> dinv (needed by the pre-scaled conversion)
    k_count<<<(N_EDGES + 255) / 256, 256, 0, stream>>>(dst, indeg, N_EDGES);
    k_prep <<<(N_NODES + 255) / 256, 256, 0, stream>>>(indeg, dinv, batch, cnt, r0, r1, N_NODES);

    // conversions (x' = dinv*x sliced; W1^T)
    k_f2bf<<<(N_NODES * 64 + 255) / 256, 256, 0, stream>>>(x, dinv, xh, N_NODES * 64);
    k_wt  <<<64, 256, 0, stream>>>(W1, Wt);

    // CSR scan + fill (col-only)
    k_scan1<<<nbScan, 256, 0, stream>>>(indeg, rp, bsums, N_NODES);
    k_scan2<<<1, 256, 0, stream>>>(bsums, nbScan);
    k_scan3<<<(N_NODES + 1 + 255) / 256, 256, 0, stream>>>(rp, bsums, N_NODES, N_EDGES);
    k_fill <<<(N_EDGES + 255) / 256, 256, 0, stream>>>(src, dst, rp, cursor, col, N_EDGES);

    // layer 1: sliced gather -> MFMA GEMM (+bias+relu+dinv)
    k_aggA<<<(N_NODES / 32) * 8, 256, 0, stream>>>(xh, Ab, rp, col, dinv);
    k_gemm_mfma<<<M_PAD / 64, 256, 0, stream>>>((const unsigned short*)Ab, Wt, b1, dinv,
                                                (unsigned short*)Bb);

    // classifier weight folding (tiny, independent)
    k_wcomb<<<16, 256, 0, stream>>>(W2, Wf, b2, bf, Wc, bc);

    // layer 2: sliced gather -> dense f32 Q rows (aliases xh/Ab)
    k_aggQ<<<(N_NODES / 32) * 8, 256, 0, stream>>>(Bb, Q, rp, col, dinv);

    // fused mean-pool + classifier
    k_final<<<N_GRAPHS, 128, 0, stream>>>(Q, cnt, r0, r1, Wc, bc, bf, (float*)d_out);
}

// Round 11
// 701.404 us; speedup vs baseline: 2.4484x; 2.4484x over previous
//
#include <hip/hip_runtime.h>
#include <hip/hip_bf16.h>

#define N_NODES   100000
#define N_EDGES   1600000
#define FDIM      128
#define N_GRAPHS  1024
#define N_CLASSES 32
#define SCAN_BLK  1024
#define M_PAD     100032            // padded rows for 64-row GEMM tiles
#define SLICE_U   (M_PAD * 8)       // uints per 16-feature slice (32B rows)
#define KN        25                // nodes per wave (4*KN = 100 per block)

typedef __attribute__((ext_vector_type(8))) short short8v;
typedef __attribute__((ext_vector_type(4))) float f32x4;
typedef __attribute__((ext_vector_type(2))) unsigned uint2v;

__device__ __forceinline__ float bflo(unsigned u){ union{unsigned i; float f;} c; c.i = u << 16; return c.f; }
__device__ __forceinline__ float bfhi(unsigned u){ union{unsigned i; float f;} c; c.i = u & 0xffff0000u; return c.f; }
__device__ __forceinline__ unsigned short f2bf(float f){
    union{float f; unsigned u;} c{f};
    return (unsigned short)((c.u + 0x7fffu + ((c.u >> 16) & 1u)) >> 16);
}
__device__ __forceinline__ unsigned packbf2(float a, float b){
    return (unsigned)f2bf(a) | ((unsigned)f2bf(b) << 16);
}

// ---------------------------------------------------------------------------
// fp32 x[v][128] * dinv[v] -> bf16x2 XCD-sliced X' table
__global__ void k_f2bf(const float* __restrict__ in, const float* __restrict__ dinv,
                       unsigned* __restrict__ out, int n2) {
    int i = blockIdx.x * blockDim.x + threadIdx.x;
    if (i < n2) {
        float2 v2 = ((const float2*)in)[i];
        int v = i >> 6, jp = i & 63;
        int f = jp >> 3, off = jp & 7;
        float dv = dinv[v];
        __builtin_nontemporal_store(packbf2(v2.x * dv, v2.y * dv),
                                    out + (size_t)f * SLICE_U + (size_t)v * 8 + off);
    }
}

__global__ void k_wt(const float* __restrict__ W, unsigned short* __restrict__ Wt) {
    int i = blockIdx.x * blockDim.x + threadIdx.x;   // 16384
    int k = i >> 7, n = i & 127;
    Wt[n * 128 + k] = f2bf(W[i]);
}

// ---------------------------------------------------------------------------
__global__ void k_count(const int* __restrict__ dst, int* __restrict__ indeg, int E) {
    int i = blockIdx.x * blockDim.x + threadIdx.x;
    if (i < E) atomicAdd(&indeg[dst[i]], 1);
}

// dinv + per-graph count + contiguous node range [r0,r1) (batch is sorted)
__global__ void k_prep(const int* __restrict__ indeg, float* __restrict__ dinv,
                       const int* __restrict__ batch, int* __restrict__ cnt,
                       int* __restrict__ r0, int* __restrict__ r1, int n) {
    int v = blockIdx.x * blockDim.x + threadIdx.x;
    if (v < n) {
        dinv[v] = rsqrtf((float)(indeg[v] + 1));
        int g = batch[v];
        atomicAdd(&cnt[g], 1);
        atomicMin(&r0[g], v);
        atomicMax(&r1[g], v + 1);
    }
}

__global__ void k_scan1(const int* __restrict__ in, int* __restrict__ out,
                        int* __restrict__ bsums, int n) {
    __shared__ int lds[256];
    int blk = blockIdx.x, t = threadIdx.x;
    int base = blk * SCAN_BLK + t * 4;
    int v[4];
#pragma unroll
    for (int i = 0; i < 4; ++i) v[i] = (base + i < n) ? in[base + i] : 0;
    int local = v[0] + v[1] + v[2] + v[3];
    lds[t] = local;
    __syncthreads();
    for (int off = 1; off < 256; off <<= 1) {
        int x = lds[t];
        int y = (t >= off) ? lds[t - off] : 0;
        __syncthreads();
        lds[t] = x + y;
        __syncthreads();
    }
    int excl = lds[t] - local;
    if (t == 255) bsums[blk] = lds[255];
    int run = excl;
#pragma unroll
    for (int i = 0; i < 4; ++i) {
        if (base + i < n) { out[base + i] = run; run += v[i]; }
    }
}

__global__ void k_scan2(int* __restrict__ bsums, int nb) {
    __shared__ int lds[256];
    int t = threadIdx.x;
    int orig = (t < nb) ? bsums[t] : 0;
    lds[t] = orig;
    __syncthreads();
    for (int off = 1; off < 256; off <<= 1) {
        int x = lds[t];
        int y = (t >= off) ? lds[t - off] : 0;
        __syncthreads();
        lds[t] = x + y;
        __syncthreads();
    }
    if (t < nb) bsums[t] = lds[t] - orig;
}

__global__ void k_scan3(int* __restrict__ rp, const int* __restrict__ boffs, int n, int E) {
    int i = blockIdx.x * blockDim.x + threadIdx.x;
    if (i < n) rp[i] += boffs[i / SCAN_BLK];
    if (i == n) rp[n] = E;
}

// CSR fill: col only (weights folded into pre-scaled tables)
__global__ void k_fill(const int* __restrict__ src, const int* __restrict__ dst,
                       const int* __restrict__ rp, int* __restrict__ cursor,
                       int* __restrict__ col, int E) {
    int i = blockIdx.x * blockDim.x + threadIdx.x;
    if (i < E) {
        int d = dst[i];
        int p = atomicAdd(&cursor[d], 1);
        col[rp[d] + p] = src[i];
    }
}

// ---------------------------------------------------------------------------
// XCD-sliced gather v3: slice f = blockIdx&7 (3.2MB slice L2-resident on XCD f).
// One node per wave-iteration; 16 slots x 4 lanes (uint2 = 8B/lane, 32B row per
// slot); 2 predicated record batches cover deg<=31; rare uniform tail loop.
// 1-node-lookahead pipeline with scalar state; node loop NOT unrolled (VGPR!).
// Slot 0 = self; out = dinv[v] * (sum of pre-scaled rows).
// MODE 0: store sliced bf16; MODE 1: store dense f32 Q rows.
template<int MODE>
__global__ __launch_bounds__(256) void k_agg(
    const unsigned* __restrict__ Xs, unsigned* __restrict__ Os, float* __restrict__ Q,
    const int* __restrict__ rp, const int* __restrict__ col,
    const float* __restrict__ dinv)
{
    int lane = threadIdx.x & 63;
    int wv   = threadIdx.x >> 6;
    int f    = blockIdx.x & 7;
    int ri   = lane >> 2;
    int q    = lane & 3;
    const unsigned* XT = Xs + (size_t)f * SLICE_U;
    unsigned* OT       = Os + (size_t)f * SLICE_U;

    int v  = (blockIdx.x >> 3) * (4 * KN) + wv * KN;
    int e0 = rp[v];
    int L  = rp[v + 1] - e0 + 1;
    int r1 = (ri < L) ? ((ri == 0) ? v : col[e0 + ri - 1]) : -1;
    int r2 = (ri + 16 < L) ? col[e0 + ri + 15] : -1;

#pragma unroll 1
    for (int j = 0; j < KN; ++j) {
        int vn = v + 1;
        int e0n = 0, Lnx = 0, r1n = -1, r2n = -1;
        if (j + 1 < KN) {
            e0n = e0 + L - 1;            // rp[v+1], carried
            Lnx = rp[vn + 1] - e0n + 1;
            r1n = (ri < Lnx) ? ((ri == 0) ? vn : col[e0n + ri - 1]) : -1;
            r2n = (ri + 16 < Lnx) ? col[e0n + ri + 15] : -1;
        }
        uint2v u1 = {0u, 0u}, u2 = {0u, 0u};
        if (r1 >= 0) u1 = *(const uint2v*)(XT + (size_t)r1 * 8 + q * 2);
        if (r2 >= 0) u2 = *(const uint2v*)(XT + (size_t)r2 * 8 + q * 2);
        float a0 = bflo(u1.x) + bflo(u2.x);
        float a1 = bfhi(u1.x) + bfhi(u2.x);
        float a2 = bflo(u1.y) + bflo(u2.y);
        float a3 = bfhi(u1.y) + bfhi(u2.y);
        if (__builtin_expect(L > 32, 0)) {
            for (int b = ri + 32; b < L; b += 16) {
                int s = col[e0 + b - 1];
                uint2v u = *(const uint2v*)(XT + (size_t)s * 8 + q * 2);
                a0 += bflo(u.x); a1 += bfhi(u.x);
                a2 += bflo(u.y); a3 += bfhi(u.y);
            }
        }
#pragma unroll
        for (int off = 4; off < 64; off <<= 1) {
            a0 += __shfl_xor(a0, off, 64);
            a1 += __shfl_xor(a1, off, 64);
            a2 += __shfl_xor(a2, off, 64);
            a3 += __shfl_xor(a3, off, 64);
        }
        float dvv = dinv[v];
        a0 *= dvv; a1 *= dvv; a2 *= dvv; a3 *= dvv;

        if (ri == 0) {
            if constexpr (MODE == 0) {
                uint2v o;
                o.x = packbf2(a0, a1);
                o.y = packbf2(a2, a3);
                __builtin_nontemporal_store(o, (uint2v*)(OT + (size_t)v * 8 + q * 2));
            } else {
                f32x4 o;
                o.x = a0; o.y = a1; o.z = a2; o.w = a3;
                __builtin_nontemporal_store(o,
                    (f32x4*)(Q + (size_t)v * FDIM + f * 16 + q * 4));
            }
        }
        v = vn; e0 = e0n; L = Lnx; r1 = r1n; r2 = r2n;
    }
}

// ---------------------------------------------------------------------------
// B = relu(A @ W1 + b1) * dinv[row]  (H' pre-scale folded into epilogue)
__global__ __launch_bounds__(256) void k_gemm_mfma(
    const unsigned short* __restrict__ A, const unsigned short* __restrict__ Wt,
    const float* __restrict__ bias, const float* __restrict__ dinv,
    unsigned short* __restrict__ B)
{
    int lane = threadIdx.x & 63;
    int wv = threadIdx.x >> 6;
    size_t row0 = (size_t)blockIdx.x * 64 + (size_t)wv * 16;
    int r = lane & 15, g = lane >> 4;

    short8v af[4];
#pragma unroll
    for (int ks = 0; ks < 4; ++ks) {
        int fa  = 2 * ks + (g >> 1);          // slice of features ks*32 + g*8
        int off = (g & 1) * 8;
        af[ks] = *(const short8v*)(A + (size_t)fa * SLICE_U * 2 + (row0 + r) * 16 + off);
    }

    f32x4 acc[8];
#pragma unroll
    for (int ct = 0; ct < 8; ++ct) {
        f32x4 a = {0.f, 0.f, 0.f, 0.f};
        const unsigned short* wrow = Wt + (ct * 16 + r) * FDIM + g * 8;
#pragma unroll
        for (int ks = 0; ks < 4; ++ks) {
            short8v bfr = *(const short8v*)(wrow + ks * 32);
            a = __builtin_amdgcn_mfma_f32_16x16x32_bf16(af[ks], bfr, a, 0, 0, 0);
        }
        acc[ct] = a;
    }

#pragma unroll
    for (int ct = 0; ct < 8; ++ct) {
        float bs = bias[ct * 16 + r];
#pragma unroll
        for (int i = 0; i < 4; ++i) {
            size_t row = row0 + g * 4 + i;
            if (row < N_NODES) {
                float vv = fmaxf(acc[ct][i] + bs, 0.f) * dinv[row];
                __builtin_nontemporal_store(f2bf(vv),
                    B + (size_t)ct * SLICE_U * 2 + row * 16 + r);
            }
        }
    }
}

// ---------------------------------------------------------------------------
__global__ void k_wcomb(const float* __restrict__ W2, const float* __restrict__ Wf,
                        const float* __restrict__ b2, const float* __restrict__ bf,
                        float* __restrict__ Wc, float* __restrict__ bc) {
    int idx = blockIdx.x * blockDim.x + threadIdx.x;
    if (idx < 128 * 32) {
        int k = idx >> 5, c = idx & 31;
        float acc = 0.0f;
        for (int m = 0; m < 128; ++m) acc += W2[k * 128 + m] * Wf[m * 32 + c];
        Wc[idx] = acc;
    }
    if (idx < 32) {
        float acc = bf[idx];
        for (int m = 0; m < 128; ++m) acc += b2[m] * Wf[m * 32 + idx];
        bc[idx] = acc;
    }
}

// fused pool + classifier: per graph, stream contiguous Q rows (batch sorted),
// mean, then fold through Wc. Zero atomics.
__global__ __launch_bounds__(128) void k_final(
    const float* __restrict__ Q, const int* __restrict__ cnt,
    const int* __restrict__ r0, const int* __restrict__ r1,
    const float* __restrict__ Wc, const float* __restrict__ bc,
    const float* __restrict__ bf, float* __restrict__ out)
{
    __shared__ float p[128];
    int g = blockIdx.x, t = threadIdx.x;
    int c_ = cnt[g];
    int v0 = r0[g], v1 = r1[g];
    float s0 = 0.f, s1 = 0.f;
    int v = v0;
    for (; v + 1 < v1; v += 2) {
        s0 += Q[(size_t)v * FDIM + t];
        s1 += Q[(size_t)(v + 1) * FDIM + t];
    }
    if (v < v1) s0 += Q[(size_t)v * FDIM + t];
    float inv = (c_ > 0) ? 1.0f / (float)c_ : 0.0f;
    p[t] = (s0 + s1) * inv;
    __syncthreads();
    if (t < N_CLASSES) {
        float acc = (c_ > 0) ? bc[t] : bf[t];
#pragma unroll
        for (int k = 0; k < 128; ++k) acc = fmaf(p[k], Wc[k * 32 + t], acc);
        out[(size_t)g * N_CLASSES + t] = acc;
    }
}

// ---------------------------------------------------------------------------
extern "C" void kernel_launch(void* const* d_in, const int* in_sizes, int n_in,
                              void* d_out, int out_size, void* d_ws, size_t ws_size,
                              hipStream_t stream) {
    const float* x    = (const float*)d_in[0];
    const int*   ei   = (const int*)d_in[1];
    const int*   batch= (const int*)d_in[2];
    const float* W1   = (const float*)d_in[3];
    const float* b1   = (const float*)d_in[4];
    const float* W2   = (const float*)d_in[5];
    const float* b2   = (const float*)d_in[6];
    const float* Wf   = (const float*)d_in[7];
    const float* bf   = (const float*)d_in[8];
    const int* src = ei;
    const int* dst = ei + N_EDGES;

    char* w = (char*)d_ws;
    auto alloc = [&](size_t bytes) { char* p = w; w += (bytes + 255) & ~255ull; return p; };
    int*      indeg  = (int*)     alloc((size_t)N_NODES * 4);
    float*    dinv   = (float*)   alloc((size_t)N_NODES * 4);
    int*      rp     = (int*)     alloc((size_t)(N_NODES + 1) * 4);
    int*      cursor = (int*)     alloc((size_t)N_NODES * 4);
    int*      bsums  = (int*)     alloc(1024 * 4);
    int*      col    = (int*)     alloc((size_t)N_EDGES * 4);
    unsigned* xh     = (unsigned*)alloc((size_t)SLICE_U * 8 * 4);   // sliced bf16x2 X'
    unsigned* Ab     = (unsigned*)alloc((size_t)SLICE_U * 8 * 4);   // sliced bf16x2 A
    unsigned* Bb     = (unsigned*)alloc((size_t)SLICE_U * 8 * 4);   // sliced bf16x2 H'
    unsigned short* Wt = (unsigned short*)alloc(128 * 128 * 2);
    int*      cnt    = (int*)     alloc((size_t)N_GRAPHS * 4);
    int*      r0     = (int*)     alloc((size_t)N_GRAPHS * 4);
    int*      r1     = (int*)     alloc((size_t)N_GRAPHS * 4);
    float*    Wc     = (float*)   alloc(128 * 32 * 4);
    float*    bc     = (float*)   alloc(32 * 4);
    // Q (dense f32 [M_PAD][128], 51.2MB) aliases xh+Ab (dead after GEMM;
    // contiguous and exactly M_PAD*128*4 bytes combined)
    float*    Q      = (float*)xh;

    hipMemsetAsync(indeg,  0,    (size_t)N_NODES * 4, stream);
    hipMemsetAsync(cursor, 0,    (size_t)N_NODES * 4, stream);
    hipMemsetAsync(cnt,    0,    (size_t)N_GRAPHS * 4, stream);
    hipMemsetAsync(r0,     0x7f, (size_t)N_GRAPHS * 4, stream);
    hipMemsetAsync(r1,     0,    (size_t)N_GRAPHS * 4, stream);

    const int nbScan = (N_NODES + SCAN_BLK - 1) / SCAN_BLK;   // 98

    // degrees -> dinv (needed by the pre-scaled conversion)
    k_count<<<(N_EDGES + 255) / 256, 256, 0, stream>>>(dst, indeg, N_EDGES);
    k_prep <<<(N_NODES + 255) / 256, 256, 0, stream>>>(indeg, dinv, batch, cnt, r0, r1, N_NODES);

    // conversions (x' = dinv*x sliced; W1^T)
    k_f2bf<<<(N_NODES * 64 + 255) / 256, 256, 0, stream>>>(x, dinv, xh, N_NODES * 64);
    k_wt  <<<64, 256, 0, stream>>>(W1, Wt);

    // CSR scan + fill (col-only)
    k_scan1<<<nbScan, 256, 0, stream>>>(indeg, rp, bsums, N_NODES);
    k_scan2<<<1, 256, 0, stream>>>(bsums, nbScan);
    k_scan3<<<(N_NODES + 1 + 255) / 256, 256, 0, stream>>>(rp, bsums, N_NODES, N_EDGES);
    k_fill <<<(N_EDGES + 255) / 256, 256, 0, stream>>>(src, dst, rp, cursor, col, N_EDGES);

    // layer 1: sliced gather -> MFMA GEMM (+bias+relu+dinv)
    k_agg<0><<<(N_NODES / (4 * KN)) * 8, 256, 0, stream>>>(xh, Ab, nullptr, rp, col, dinv);
    k_gemm_mfma<<<M_PAD / 64, 256, 0, stream>>>((const unsigned short*)Ab, Wt, b1, dinv,
                                                (unsigned short*)Bb);

    // classifier weight folding (tiny, independent)
    k_wcomb<<<16, 256, 0, stream>>>(W2, Wf, b2, bf, Wc, bc);

    // layer 2: sliced gather -> dense f32 Q rows (aliases xh/Ab)
    k_agg<1><<<(N_NODES / (4 * KN)) * 8, 256, 0, stream>>>(Bb, Bb, Q, rp, col, dinv);

    // fused mean-pool + classifier
    k_final<<<N_GRAPHS, 128, 0, stream>>>(Q, cnt, r0, r1, Wc, bc, bf, (float*)d_out);
}